// Round 7
// baseline (52.372 us; speedup 1.0000x reference)
//
#include <hip/hip_runtime.h>
#include <math.h>

// VectorQuantizer: B=4, T=2048, DIM=64, NUM_CODES=512
// out = [ k as float (8192) | z_q (8192*64) ]
//
// R6: three dispatches.
//  k0: transpose inp -> inpT[64][8192] (coalesced both sides) so k1's
//      query loads are single-segment coalesced instead of 64-seg gathers.
//  k1: lane = query, codes split 32 ways (16/wave), wave-uniform broadcast
//      c-row float4 loads, 4-float4 live window (sched_barrier-pinned, no
//      spill at 128-VGPR cap), 4096 waves = 4 waves/SIMD, zero tail.
//  k2: validated finalize (lexicographic reduce, k + z_q gather).
// Distance math bit-matches the validated path: acc[d&7] ascending-dim
// accumulation, fixed combine tree, IEEE sqrtf, strict-< ascending argmin.

#define NQ      8192
#define VDIM    64
#define NCODES  512
#define NCHUNK  32
#define CPC     (NCODES / NCHUNK)     // 16 codes per chunk

// ---------------- Kernel 0: transpose inp[NQ][64] -> inpT[64][NQ] ----------
__global__ __launch_bounds__(256) void vq_transpose_kernel(
    const float* __restrict__ inp,    // [NQ][VDIM]
    float* __restrict__ inpT)         // [VDIM][NQ]
{
    __shared__ float t[64][65];       // +1 pad: conflict-free column reads
    const int tid = threadIdx.x;
    const int r0  = blockIdx.x * 64;  // 128 blocks x 64 rows

#pragma unroll
    for (int it = 0; it < 16; ++it) {
        int flat = tid + it * 256;    // 0..4095
        int r = flat >> 6;            // 0..63
        int c = flat & 63;
        t[r][c] = inp[(size_t)(r0 + r) * VDIM + c];   // coalesced rows
    }
    __syncthreads();
#pragma unroll
    for (int it = 0; it < 16; ++it) {
        int flat = tid + it * 256;
        int d = flat >> 6;            // dim
        int r = flat & 63;            // row within tile
        inpT[(size_t)d * NQ + r0 + r] = t[r][d];      // coalesced writes
    }
}

// ---------------- Kernel 1: partial argmin over 16-code chunks -------------
__global__ __launch_bounds__(256, 4) void vq_dist_kernel(
    const float* __restrict__ inpT,    // [VDIM][NQ]
    const float* __restrict__ table,   // [NCODES][VDIM]
    float* __restrict__ wnorm,         // [NCHUNK][NQ]
    int* __restrict__ widx)            // [NCHUNK][NQ]
{
    const int lane  = threadIdx.x & 63;
    const int wave  = threadIdx.x >> 6;
    const int chunk = blockIdx.x & (NCHUNK - 1);     // code chunk (fast dim)
    const int qg    = (blockIdx.x >> 5) * 4 + wave;  // query group 0..127
    const int q     = qg * 64 + lane;

    // Query vector: 64 coalesced single-segment loads (dim-major layout).
    float qv[VDIM];
#pragma unroll
    for (int d = 0; d < VDIM; ++d) qv[d] = inpT[(size_t)d * NQ + q];

    float best = INFINITY;
    int   bidx = 0;

#pragma clang loop unroll(disable)
    for (int c = 0; c < CPC; ++c) {
        const int code = chunk * CPC + c;
        const float4* crow = reinterpret_cast<const float4*>(table + (size_t)code * VDIM);

        float acc[8];
#pragma unroll
        for (int m = 0; m < 8; ++m) acc[m] = 0.0f;

        // 4 batches of 4 uniform float4 loads (16 dims each); elem e -> acc[e&7],
        // ascending dim order (bit-exact vs validated path). sched_barrier(0)
        // between batches pins the live cv window to 16 VGPRs (no spill).
#define VQ_BATCH(B)                                                          \
        {                                                                    \
            float4 cv0 = crow[(B) * 4 + 0];                                  \
            float4 cv1 = crow[(B) * 4 + 1];                                  \
            float4 cv2 = crow[(B) * 4 + 2];                                  \
            float4 cv3 = crow[(B) * 4 + 3];                                  \
            float d0, d1, d2, d3;                                            \
            d0 = qv[(B)*16+ 0] - cv0.x; d1 = qv[(B)*16+ 1] - cv0.y;          \
            d2 = qv[(B)*16+ 2] - cv0.z; d3 = qv[(B)*16+ 3] - cv0.w;          \
            acc[0] = __builtin_fmaf(d0, d0, acc[0]);                         \
            acc[1] = __builtin_fmaf(d1, d1, acc[1]);                         \
            acc[2] = __builtin_fmaf(d2, d2, acc[2]);                         \
            acc[3] = __builtin_fmaf(d3, d3, acc[3]);                         \
            d0 = qv[(B)*16+ 4] - cv1.x; d1 = qv[(B)*16+ 5] - cv1.y;          \
            d2 = qv[(B)*16+ 6] - cv1.z; d3 = qv[(B)*16+ 7] - cv1.w;          \
            acc[4] = __builtin_fmaf(d0, d0, acc[4]);                         \
            acc[5] = __builtin_fmaf(d1, d1, acc[5]);                         \
            acc[6] = __builtin_fmaf(d2, d2, acc[6]);                         \
            acc[7] = __builtin_fmaf(d3, d3, acc[7]);                         \
            d0 = qv[(B)*16+ 8] - cv2.x; d1 = qv[(B)*16+ 9] - cv2.y;          \
            d2 = qv[(B)*16+10] - cv2.z; d3 = qv[(B)*16+11] - cv2.w;          \
            acc[0] = __builtin_fmaf(d0, d0, acc[0]);                         \
            acc[1] = __builtin_fmaf(d1, d1, acc[1]);                         \
            acc[2] = __builtin_fmaf(d2, d2, acc[2]);                         \
            acc[3] = __builtin_fmaf(d3, d3, acc[3]);                         \
            d0 = qv[(B)*16+12] - cv3.x; d1 = qv[(B)*16+13] - cv3.y;          \
            d2 = qv[(B)*16+14] - cv3.z; d3 = qv[(B)*16+15] - cv3.w;          \
            acc[4] = __builtin_fmaf(d0, d0, acc[4]);                         \
            acc[5] = __builtin_fmaf(d1, d1, acc[5]);                         \
            acc[6] = __builtin_fmaf(d2, d2, acc[6]);                         \
            acc[7] = __builtin_fmaf(d3, d3, acc[7]);                         \
        }

        VQ_BATCH(0)
        __builtin_amdgcn_sched_barrier(0);
        VQ_BATCH(1)
        __builtin_amdgcn_sched_barrier(0);
        VQ_BATCH(2)
        __builtin_amdgcn_sched_barrier(0);
        VQ_BATCH(3)
        __builtin_amdgcn_sched_barrier(0);
#undef VQ_BATCH

        float s = ((acc[0] + acc[1]) + (acc[2] + acc[3]))
                + ((acc[4] + acc[5]) + (acc[6] + acc[7]));
        float n = sqrtf(s);               // same norm-space compare as ref
        if (n < best) {                   // strict <, ascending code index
            best = n;
            bidx = code;
        }
    }

    wnorm[(size_t)chunk * NQ + q] = best;
    widx [(size_t)chunk * NQ + q] = bidx;
}

// ---------------- Kernel 2: finalize (validated) ---------------------------
__global__ __launch_bounds__(256) void vq_finalize_kernel(
    const float* __restrict__ table,
    const float* __restrict__ wnorm,
    const int* __restrict__ widx,
    float* __restrict__ out)
{
    const int gid = blockIdx.x * 256 + threadIdx.x;   // 0 .. NQ*64
    const int q = gid >> 6;
    const int d = gid & 63;

    float best = INFINITY;
    int   bidx = 0;
#pragma unroll
    for (int p = 0; p < NCHUNK; ++p) {
        float n = wnorm[(size_t)p * NQ + q];
        int   i = widx [(size_t)p * NQ + q];
        if (n < best || (n == best && i < bidx)) { best = n; bidx = i; }
    }

    out[NQ + (size_t)q * VDIM + d] = table[(size_t)bidx * VDIM + d];
    if (d == 0) out[q] = (float)bidx;
}

extern "C" void kernel_launch(void* const* d_in, const int* in_sizes, int n_in,
                              void* d_out, int out_size, void* d_ws, size_t ws_size,
                              hipStream_t stream) {
    const float* inp   = (const float*)d_in[0];   // [4,2048,64] fp32
    const float* table = (const float*)d_in[1];   // [512,64]    fp32
    float* out = (float*)d_out;

    float* inpT  = (float*)d_ws;                          // 64*8192 floats (2 MB)
    float* wnorm = inpT + (size_t)VDIM * NQ;              // 32*8192 floats (1 MB)
    int*   widx  = (int*)(wnorm + (size_t)NCHUNK * NQ);   // 32*8192 ints   (1 MB)

    vq_transpose_kernel<<<dim3(NQ / 64), dim3(256), 0, stream>>>(inp, inpT);
    vq_dist_kernel<<<dim3(NCHUNK * 32), dim3(256), 0, stream>>>(inpT, table, wnorm, widx);
    vq_finalize_kernel<<<dim3((NQ * VDIM) / 256), dim3(256), 0, stream>>>(table, wnorm, widx, out);
}

// Round 8
// 47.872 us; speedup vs baseline: 1.0940x; 1.0940x over previous
//
#include <hip/hip_runtime.h>
#include <math.h>

// VectorQuantizer: B=4, T=2048, DIM=64, NUM_CODES=512
// out = [ k as float (8192) | z_q (8192*64) ]
//
// R7 = R0 recipe (wave-uniform broadcast c-row loads, compiler-scheduled,
// lane = query with qv[64] in VGPRs) + two fixes R0's model lacked:
//   - NCHUNK 16 -> 32: 4096 waves = 16 waves/CU (R0 had 8) for latency hiding
//   - __launch_bounds__(256,3): ~170-VGPR budget (R5/R6's (256,4) forced a
//     128 cap under a ~100+pipelining live set -> suspected spill, the R2
//     failure mode). No sched_barriers, no transpose.
// Distance math bit-matches the validated path: acc[d&7] ascending-dim
// accumulation, fixed combine tree, IEEE sqrtf, strict-< ascending argmin.

#define NQ      8192
#define VDIM    64
#define NCODES  512
#define NCHUNK  32
#define CPC     (NCODES / NCHUNK)     // 16 codes per chunk

__global__ __launch_bounds__(256, 3) void vq_dist_kernel(
    const float* __restrict__ inp,     // [NQ][VDIM]
    const float* __restrict__ table,   // [NCODES][VDIM]
    float* __restrict__ wnorm,         // [NCHUNK][NQ]
    int* __restrict__ widx)            // [NCHUNK][NQ]
{
    const int lane  = threadIdx.x & 63;
    const int wave  = threadIdx.x >> 6;
    const int chunk = blockIdx.x & (NCHUNK - 1);     // code chunk (fast dim)
    const int qg    = (blockIdx.x >> 5) * 4 + wave;  // query group 0..127
    const int q     = qg * 64 + lane;

    // Query vector into registers: 16 x float4 (once per wave, amortized
    // over 512 codes -- gather cost negligible, no transpose needed).
    float qv[VDIM];
    {
        const float4* qp = reinterpret_cast<const float4*>(inp + (size_t)q * VDIM);
#pragma unroll
        for (int i = 0; i < 16; ++i) {
            float4 v = qp[i];
            qv[4*i+0] = v.x; qv[4*i+1] = v.y; qv[4*i+2] = v.z; qv[4*i+3] = v.w;
        }
    }

    float best = INFINITY;
    int   bidx = 0;

#pragma clang loop unroll(disable)
    for (int c = 0; c < CPC; ++c) {
        const int code = chunk * CPC + c;
        const float4* crow = reinterpret_cast<const float4*>(table + (size_t)code * VDIM);

        float acc[8];
#pragma unroll
        for (int m = 0; m < 8; ++m) acc[m] = 0.0f;

        // 4 sub-batches: 4 wave-uniform float4 loads + 32 sub/fma each.
        // Elem e -> acc[e&7], updates in ascending dim order (bit-exact).
#pragma unroll
        for (int b = 0; b < 4; ++b) {
            float4 cv0 = crow[b * 4 + 0];
            float4 cv1 = crow[b * 4 + 1];
            float4 cv2 = crow[b * 4 + 2];
            float4 cv3 = crow[b * 4 + 3];
            const float* qb = qv + b * 16;
            float d0, d1, d2, d3;
            d0 = qb[ 0] - cv0.x; d1 = qb[ 1] - cv0.y; d2 = qb[ 2] - cv0.z; d3 = qb[ 3] - cv0.w;
            acc[0] = __builtin_fmaf(d0, d0, acc[0]);
            acc[1] = __builtin_fmaf(d1, d1, acc[1]);
            acc[2] = __builtin_fmaf(d2, d2, acc[2]);
            acc[3] = __builtin_fmaf(d3, d3, acc[3]);
            d0 = qb[ 4] - cv1.x; d1 = qb[ 5] - cv1.y; d2 = qb[ 6] - cv1.z; d3 = qb[ 7] - cv1.w;
            acc[4] = __builtin_fmaf(d0, d0, acc[4]);
            acc[5] = __builtin_fmaf(d1, d1, acc[5]);
            acc[6] = __builtin_fmaf(d2, d2, acc[6]);
            acc[7] = __builtin_fmaf(d3, d3, acc[7]);
            d0 = qb[ 8] - cv2.x; d1 = qb[ 9] - cv2.y; d2 = qb[10] - cv2.z; d3 = qb[11] - cv2.w;
            acc[0] = __builtin_fmaf(d0, d0, acc[0]);
            acc[1] = __builtin_fmaf(d1, d1, acc[1]);
            acc[2] = __builtin_fmaf(d2, d2, acc[2]);
            acc[3] = __builtin_fmaf(d3, d3, acc[3]);
            d0 = qb[12] - cv3.x; d1 = qb[13] - cv3.y; d2 = qb[14] - cv3.z; d3 = qb[15] - cv3.w;
            acc[4] = __builtin_fmaf(d0, d0, acc[4]);
            acc[5] = __builtin_fmaf(d1, d1, acc[5]);
            acc[6] = __builtin_fmaf(d2, d2, acc[6]);
            acc[7] = __builtin_fmaf(d3, d3, acc[7]);
        }

        float s = ((acc[0] + acc[1]) + (acc[2] + acc[3]))
                + ((acc[4] + acc[5]) + (acc[6] + acc[7]));
        float n = sqrtf(s);               // same norm-space compare as ref
        if (n < best) {                   // strict <, ascending code index
            best = n;
            bidx = code;
        }
    }

    wnorm[(size_t)chunk * NQ + q] = best;
    widx [(size_t)chunk * NQ + q] = bidx;
}

// Reduce the 32 chunk-partials per query (ascending -> first-occurrence
// tie-break), write k (as float) and gather z_q coalesced. (Validated.)
__global__ __launch_bounds__(256) void vq_finalize_kernel(
    const float* __restrict__ table,
    const float* __restrict__ wnorm,
    const int* __restrict__ widx,
    float* __restrict__ out)
{
    const int gid = blockIdx.x * 256 + threadIdx.x;   // 0 .. NQ*64
    const int q = gid >> 6;
    const int d = gid & 63;

    float best = INFINITY;
    int   bidx = 0;
#pragma unroll
    for (int p = 0; p < NCHUNK; ++p) {
        float n = wnorm[(size_t)p * NQ + q];
        int   i = widx [(size_t)p * NQ + q];
        if (n < best || (n == best && i < bidx)) { best = n; bidx = i; }
    }

    out[NQ + (size_t)q * VDIM + d] = table[(size_t)bidx * VDIM + d];
    if (d == 0) out[q] = (float)bidx;
}

extern "C" void kernel_launch(void* const* d_in, const int* in_sizes, int n_in,
                              void* d_out, int out_size, void* d_ws, size_t ws_size,
                              hipStream_t stream) {
    const float* inp   = (const float*)d_in[0];   // [4,2048,64] fp32
    const float* table = (const float*)d_in[1];   // [512,64]    fp32
    float* out = (float*)d_out;

    float* wnorm = (float*)d_ws;                        // NCHUNK*NQ floats (1 MB)
    int*   widx  = (int*)(wnorm + (size_t)NCHUNK * NQ); // NCHUNK*NQ ints   (1 MB)

    // 32 chunks x 32 query-quads = 1024 blocks x 256 thr = 4096 waves
    vq_dist_kernel<<<dim3(NCHUNK * 32), dim3(256), 0, stream>>>(inp, table, wnorm, widx);
    vq_finalize_kernel<<<dim3((NQ * VDIM) / 256), dim3(256), 0, stream>>>(table, wnorm, widx, out);
}

// Round 9
// 35.022 us; speedup vs baseline: 1.4954x; 1.3669x over previous
//
#include <hip/hip_runtime.h>
#include <math.h>

// VectorQuantizer: B=4, T=2048, DIM=64, NUM_CODES=512
// out = [ k as float (8192) | z_q (8192*64) ]
//
// R8: two-code-interleaved broadcast kernel. Each wave (lane = query)
// processes a 32-code chunk as 16 ADJACENT PAIRS; the two codes' load+FMA
// streams are independent, giving the scheduler real work to issue inside
// each other's load-latency shadows (R0..R7 all measured ~1200 cyc/code =
// serialized load-use; compute is only ~280). No launch_bounds min-waves
// (compiler free, ~140 VGPR expected, no spill), no sched_barriers.
// Per-code math is bit-identical to the validated path: acc[d&7]
// ascending-dim accumulation, fixed combine tree, IEEE sqrtf, strict-<
// ascending-index argmin (pair compared A-then-B).

#define NQ      8192
#define VDIM    64
#define NCODES  512
#define NCHUNK  16
#define CPC     (NCODES / NCHUNK)     // 32 codes per chunk

__global__ __launch_bounds__(256) void vq_dist_kernel(
    const float* __restrict__ inp,     // [NQ][VDIM]
    const float* __restrict__ table,   // [NCODES][VDIM]
    float* __restrict__ wnorm,         // [NCHUNK][NQ]
    int* __restrict__ widx)            // [NCHUNK][NQ]
{
    const int lane  = threadIdx.x & 63;
    const int wave  = threadIdx.x >> 6;
    const int chunk = blockIdx.x & (NCHUNK - 1);     // code chunk (fast dim)
    const int qg    = (blockIdx.x >> 4) * 4 + wave;  // query group 0..127
    const int q     = qg * 64 + lane;

    // Query vector into registers (16 x float4; once per wave).
    float qv[VDIM];
    {
        const float4* qp = reinterpret_cast<const float4*>(inp + (size_t)q * VDIM);
#pragma unroll
        for (int i = 0; i < 16; ++i) {
            float4 v = qp[i];
            qv[4*i+0] = v.x; qv[4*i+1] = v.y; qv[4*i+2] = v.z; qv[4*i+3] = v.w;
        }
    }

    float best = INFINITY;
    int   bidx = 0;

    const float4* tb = reinterpret_cast<const float4*>(table);

    // 32 VALU ops for batch B of one code: dims B*16 .. B*16+15 -> acc[e&7],
    // ascending dim order within the batch (bit-exact vs validated path).
#define VQ_COMP(cv0, cv1, cv2, cv3, A, B)                                    \
    {                                                                        \
        float d0, d1, d2, d3;                                                \
        d0 = qv[(B)*16+ 0] - cv0.x; d1 = qv[(B)*16+ 1] - cv0.y;              \
        d2 = qv[(B)*16+ 2] - cv0.z; d3 = qv[(B)*16+ 3] - cv0.w;              \
        A[0] = __builtin_fmaf(d0, d0, A[0]);                                 \
        A[1] = __builtin_fmaf(d1, d1, A[1]);                                 \
        A[2] = __builtin_fmaf(d2, d2, A[2]);                                 \
        A[3] = __builtin_fmaf(d3, d3, A[3]);                                 \
        d0 = qv[(B)*16+ 4] - cv1.x; d1 = qv[(B)*16+ 5] - cv1.y;              \
        d2 = qv[(B)*16+ 6] - cv1.z; d3 = qv[(B)*16+ 7] - cv1.w;              \
        A[4] = __builtin_fmaf(d0, d0, A[4]);                                 \
        A[5] = __builtin_fmaf(d1, d1, A[5]);                                 \
        A[6] = __builtin_fmaf(d2, d2, A[6]);                                 \
        A[7] = __builtin_fmaf(d3, d3, A[7]);                                 \
        d0 = qv[(B)*16+ 8] - cv2.x; d1 = qv[(B)*16+ 9] - cv2.y;              \
        d2 = qv[(B)*16+10] - cv2.z; d3 = qv[(B)*16+11] - cv2.w;              \
        A[0] = __builtin_fmaf(d0, d0, A[0]);                                 \
        A[1] = __builtin_fmaf(d1, d1, A[1]);                                 \
        A[2] = __builtin_fmaf(d2, d2, A[2]);                                 \
        A[3] = __builtin_fmaf(d3, d3, A[3]);                                 \
        d0 = qv[(B)*16+12] - cv3.x; d1 = qv[(B)*16+13] - cv3.y;              \
        d2 = qv[(B)*16+14] - cv3.z; d3 = qv[(B)*16+15] - cv3.w;              \
        A[4] = __builtin_fmaf(d0, d0, A[4]);                                 \
        A[5] = __builtin_fmaf(d1, d1, A[5]);                                 \
        A[6] = __builtin_fmaf(d2, d2, A[6]);                                 \
        A[7] = __builtin_fmaf(d3, d3, A[7]);                                 \
    }

#pragma clang loop unroll(disable)
    for (int cp = 0; cp < CPC; cp += 2) {
        const int codeA = chunk * CPC + cp;          // even
        const float4* ca = tb + (size_t)codeA * 16;
        const float4* cb = ca + 16;                  // codeA+1

        float accA[8], accB[8];
#pragma unroll
        for (int m = 0; m < 8; ++m) { accA[m] = 0.0f; accB[m] = 0.0f; }

        // Batch 0 loads for both streams, then skewed load/compute:
        // while computing stream X batch b, stream Y batch b (and X batch
        // b+1) loads are already in flight -- two independent chains.
        float4 a0 = ca[0],  a1 = ca[1],  a2 = ca[2],  a3 = ca[3];
        float4 b0 = cb[0],  b1 = cb[1],  b2 = cb[2],  b3 = cb[3];
        float4 a4 = ca[4],  a5 = ca[5],  a6 = ca[6],  a7 = ca[7];
        VQ_COMP(a0, a1, a2, a3, accA, 0)
        float4 b4 = cb[4],  b5 = cb[5],  b6 = cb[6],  b7 = cb[7];
        VQ_COMP(b0, b1, b2, b3, accB, 0)
        float4 a8 = ca[8],  a9 = ca[9],  a10 = ca[10], a11 = ca[11];
        VQ_COMP(a4, a5, a6, a7, accA, 1)
        float4 b8 = cb[8],  b9 = cb[9],  b10 = cb[10], b11 = cb[11];
        VQ_COMP(b4, b5, b6, b7, accB, 1)
        float4 a12 = ca[12], a13 = ca[13], a14 = ca[14], a15 = ca[15];
        VQ_COMP(a8, a9, a10, a11, accA, 2)
        float4 b12 = cb[12], b13 = cb[13], b14 = cb[14], b15 = cb[15];
        VQ_COMP(b8, b9, b10, b11, accB, 2)
        VQ_COMP(a12, a13, a14, a15, accA, 3)
        VQ_COMP(b12, b13, b14, b15, accB, 3)

        // Combine tree (round-0 exact) + sqrt + argmin, A (lower index) first.
        float sA = ((accA[0] + accA[1]) + (accA[2] + accA[3]))
                 + ((accA[4] + accA[5]) + (accA[6] + accA[7]));
        float sB = ((accB[0] + accB[1]) + (accB[2] + accB[3]))
                 + ((accB[4] + accB[5]) + (accB[6] + accB[7]));
        float nA = sqrtf(sA);
        float nB = sqrtf(sB);
        if (nA < best) { best = nA; bidx = codeA; }
        if (nB < best) { best = nB; bidx = codeA + 1; }
    }
#undef VQ_COMP

    wnorm[(size_t)chunk * NQ + q] = best;
    widx [(size_t)chunk * NQ + q] = bidx;
}

// Reduce the 16 chunk-partials per query (ascending -> first-occurrence
// tie-break), write k (as float) and gather z_q coalesced. (Validated.)
__global__ __launch_bounds__(256) void vq_finalize_kernel(
    const float* __restrict__ table,
    const float* __restrict__ wnorm,
    const int* __restrict__ widx,
    float* __restrict__ out)
{
    const int gid = blockIdx.x * 256 + threadIdx.x;   // 0 .. NQ*64
    const int q = gid >> 6;
    const int d = gid & 63;

    float best = INFINITY;
    int   bidx = 0;
#pragma unroll
    for (int p = 0; p < NCHUNK; ++p) {
        float n = wnorm[(size_t)p * NQ + q];
        int   i = widx [(size_t)p * NQ + q];
        if (n < best || (n == best && i < bidx)) { best = n; bidx = i; }
    }

    out[NQ + (size_t)q * VDIM + d] = table[(size_t)bidx * VDIM + d];
    if (d == 0) out[q] = (float)bidx;
}

extern "C" void kernel_launch(void* const* d_in, const int* in_sizes, int n_in,
                              void* d_out, int out_size, void* d_ws, size_t ws_size,
                              hipStream_t stream) {
    const float* inp   = (const float*)d_in[0];   // [4,2048,64] fp32
    const float* table = (const float*)d_in[1];   // [512,64]    fp32
    float* out = (float*)d_out;

    float* wnorm = (float*)d_ws;                        // NCHUNK*NQ floats (512 KB)
    int*   widx  = (int*)(wnorm + (size_t)NCHUNK * NQ); // NCHUNK*NQ ints   (512 KB)

    // 16 chunks x 32 query-quads = 512 blocks x 256 thr = 2048 waves
    vq_dist_kernel<<<dim3(NCHUNK * 32), dim3(256), 0, stream>>>(inp, table, wnorm, widx);
    vq_finalize_kernel<<<dim3((NQ * VDIM) / 256), dim3(256), 0, stream>>>(table, wnorm, widx, out);
}